// Round 6
// baseline (265.689 us; speedup 1.0000x reference)
//
#include <hip/hip_runtime.h>
#include <hip/hip_bf16.h>
#include <math.h>
#include <stdint.h>

// Problem constants
#define BB 8
#define SS 1024
#define DMM 512
#define HH 8
#define DKK 32
#define DHH 64
// M = BB*SS = 8192

typedef __bf16 bf16x8 __attribute__((ext_vector_type(8)));
typedef float f32x4 __attribute__((ext_vector_type(4)));

// async 16B global->LDS (gfx950). LDS dest = wave-uniform base + lane*16.
__device__ __forceinline__ void gll16(const void* g, void* l) {
  __builtin_amdgcn_global_load_lds(
      (const __attribute__((address_space(1))) void*)(uintptr_t)g,
      (__attribute__((address_space(3))) void*)(uint32_t)(uintptr_t)l,
      16, 0, 0);
}

__device__ __forceinline__ uint4 pack8(const float4 a, const float4 b) {
  union { __hip_bfloat162 h2[4]; uint4 u; } p;
  p.h2[0] = __float22bfloat162_rn(make_float2(a.x, a.y));
  p.h2[1] = __float22bfloat162_rn(make_float2(a.z, a.w));
  p.h2[2] = __float22bfloat162_rn(make_float2(b.x, b.y));
  p.h2[3] = __float22bfloat162_rn(make_float2(b.z, b.w));
  return p.u;
}

// ---------------------------------------------------------------------------
// One cvt kernel for x + Wq|Wk|Wv (pre-phase). 2304 blocks.
// ---------------------------------------------------------------------------
__global__ __launch_bounds__(256) void cvt_pre(
    const float* __restrict__ x, const float* __restrict__ Wq,
    const float* __restrict__ Wk, const float* __restrict__ Wv,
    __bf16* __restrict__ xb, __bf16* __restrict__ Wcat) {
  size_t i = ((size_t)blockIdx.x * 256 + threadIdx.x) * 8;
  const float* s;
  __bf16* d;
  size_t off;
  if (i < 4194304) { s = x; d = xb; off = i; }
  else {
    size_t j = i - 4194304;
    d = Wcat + j;
    if (j < 131072) { s = Wq; off = j; }
    else if (j < 262144) { s = Wk; off = j - 131072; }
    else { s = Wv; off = j - 262144; }
    d = Wcat + j - off + off;  // d = Wcat + j
    float4 a = *(const float4*)&s[off];
    float4 b = *(const float4*)&s[off + 4];
    *(uint4*)&Wcat[j] = pack8(a, b);
    return;
  }
  float4 a = *(const float4*)&s[off];
  float4 b = *(const float4*)&s[off + 4];
  *(uint4*)&d[off] = pack8(a, b);
}

__global__ __launch_bounds__(256) void cvt_wof(
    const float* __restrict__ Wo, const float* __restrict__ Wf,
    __bf16* __restrict__ dWo, __bf16* __restrict__ dWf) {
  size_t i = ((size_t)blockIdx.x * 256 + threadIdx.x) * 8;
  const float* s;
  __bf16* d;
  size_t off;
  if (i < 262144) { s = Wo; d = dWo; off = i; }
  else { s = Wf; d = dWf; off = i - 262144; }
  float4 a = *(const float4*)&s[off];
  float4 b = *(const float4*)&s[off + 4];
  *(uint4*)&d[off] = pack8(a, b);
}

// ---------------------------------------------------------------------------
// bf16-input MFMA GEMM (unchanged from R5 — validated).
// ---------------------------------------------------------------------------
template <int MODE>
__global__ __launch_bounds__(256) void gemm_bf16(
    const __bf16* __restrict__ A, const __bf16* __restrict__ W,
    const float* __restrict__ bias, const float* __restrict__ resid,
    float* __restrict__ C, int N) {
  __shared__ __bf16 As[128 * 32];
  __shared__ __bf16 Bs[128 * 32];
  const int tid = threadIdx.x;
  const int n0 = blockIdx.x * 128;
  const int m0 = blockIdx.y * 128;
  const int lane = tid & 63;
  const int w = tid >> 6;
  const int wm = (w & 1) * 64, wn = (w >> 1) * 64;
  const int fr = lane & 15, quad = lane >> 4;

  const int srow = lane >> 2;
  const int schunk = (lane & 3) ^ ((lane >> 3) & 3);

  f32x4 acc[4][4];
#pragma unroll
  for (int mi = 0; mi < 4; ++mi)
#pragma unroll
    for (int ni = 0; ni < 4; ++ni) acc[mi][ni] = (f32x4){0.f, 0.f, 0.f, 0.f};

  for (int kt = 0; kt < 512; kt += 32) {
    __syncthreads();
#pragma unroll
    for (int j = 0; j < 2; ++j) {
      const int seg = w * 2 + j;
      const int row = seg * 16 + srow;
      gll16(&A[(size_t)(m0 + row) * 512 + kt + schunk * 8], &As[seg * 512]);
      gll16(&W[(size_t)(n0 + row) * 512 + kt + schunk * 8], &Bs[seg * 512]);
    }
    __syncthreads();

    bf16x8 af[4], bf[4];
    const int rsw = (quad ^ ((fr >> 1) & 3)) * 8;
#pragma unroll
    for (int mi = 0; mi < 4; ++mi)
      af[mi] = *(const bf16x8*)&As[(wm + mi * 16 + fr) * 32 + rsw];
#pragma unroll
    for (int ni = 0; ni < 4; ++ni)
      bf[ni] = *(const bf16x8*)&Bs[(wn + ni * 16 + fr) * 32 + rsw];
#pragma unroll
    for (int mi = 0; mi < 4; ++mi)
#pragma unroll
      for (int ni = 0; ni < 4; ++ni)
        acc[mi][ni] = __builtin_amdgcn_mfma_f32_16x16x32_bf16(
            af[mi], bf[ni], acc[mi][ni], 0, 0, 0);
  }

  const int er = (lane >> 4) * 4;
  const int ec = lane & 15;
#pragma unroll
  for (int mi = 0; mi < 4; ++mi) {
#pragma unroll
    for (int ni = 0; ni < 4; ++ni) {
      const int n = n0 + wn + ni * 16 + ec;
      float bsv = (MODE != 0) ? bias[n] : 0.0f;
#pragma unroll
      for (int r = 0; r < 4; ++r) {
        const int m = m0 + wm + mi * 16 + er + r;
        float v = acc[mi][ni][r];
        if (MODE == 1) {
          v += bsv + resid[(size_t)m * 512 + n];
        } else if (MODE == 2) {
          float g = v + bsv;
          g = g > 0.f ? g : 0.01f * g;
          v = resid[(size_t)m * 512 + n] + g;
        }
        C[(size_t)m * N + n] = v;
      }
    }
  }
}

// ---------------------------------------------------------------------------
// Prep (unchanged from R5): l2norm q,k -> Qg/Kg bf16; V -> Vt bf16 transposed.
// ---------------------------------------------------------------------------
__global__ __launch_bounds__(256) void prep_qkv(
    const float* __restrict__ qkv, __bf16* __restrict__ Qg,
    __bf16* __restrict__ Kg, __bf16* __restrict__ Vt) {
  __shared__ __bf16 vt[64][136];
  const int bh = blockIdx.x;
  const int b = bh >> 3, h = bh & 7;
  const int sb = blockIdx.y * 128;
  const int tid = threadIdx.x;

  {
    const int row = tid >> 1, half = tid & 1;
    const size_t rb = ((size_t)b * 1024 + sb + row) * 1024;
    {
      const float* p = qkv + rb + h * 32 + half * 16;
      float4 a[4];
      float ss = 0.f;
#pragma unroll
      for (int i = 0; i < 4; ++i) {
        a[i] = ((const float4*)p)[i];
        ss += a[i].x * a[i].x + a[i].y * a[i].y + a[i].z * a[i].z + a[i].w * a[i].w;
      }
      ss += __shfl_xor(ss, 1, 64);
      float sc = 1.0f / fmaxf(sqrtf(ss), 1e-12f);
      float4 s0 = make_float4(a[0].x * sc, a[0].y * sc, a[0].z * sc, a[0].w * sc);
      float4 s1 = make_float4(a[1].x * sc, a[1].y * sc, a[1].z * sc, a[1].w * sc);
      float4 s2 = make_float4(a[2].x * sc, a[2].y * sc, a[2].z * sc, a[2].w * sc);
      float4 s3 = make_float4(a[3].x * sc, a[3].y * sc, a[3].z * sc, a[3].w * sc);
      uint4* o = (uint4*)(Qg + ((size_t)bh * 1024 + sb + row) * 32 + half * 16);
      o[0] = pack8(s0, s1);
      o[1] = pack8(s2, s3);
    }
    {
      const float* p = qkv + rb + 256 + h * 32 + half * 16;
      float4 a[4];
      float ss = 0.f;
#pragma unroll
      for (int i = 0; i < 4; ++i) {
        a[i] = ((const float4*)p)[i];
        ss += a[i].x * a[i].x + a[i].y * a[i].y + a[i].z * a[i].z + a[i].w * a[i].w;
      }
      ss += __shfl_xor(ss, 1, 64);
      float sc = 1.0f / fmaxf(sqrtf(ss), 1e-12f);
      float4 s0 = make_float4(a[0].x * sc, a[0].y * sc, a[0].z * sc, a[0].w * sc);
      float4 s1 = make_float4(a[1].x * sc, a[1].y * sc, a[1].z * sc, a[1].w * sc);
      float4 s2 = make_float4(a[2].x * sc, a[2].y * sc, a[2].z * sc, a[2].w * sc);
      float4 s3 = make_float4(a[3].x * sc, a[3].y * sc, a[3].z * sc, a[3].w * sc);
      uint4* o = (uint4*)(Kg + ((size_t)bh * 1024 + sb + row) * 32 + half * 16);
      o[0] = pack8(s0, s1);
      o[1] = pack8(s2, s3);
    }
  }

#pragma unroll
  for (int i = 0; i < 8; ++i) {
    int idx = tid + i * 256;
    int t = idx >> 4, vd4 = (idx & 15) * 4;
    float4 v = *(const float4*)&qkv[((size_t)b * 1024 + sb + t) * 1024 + 512 + h * 64 + vd4];
    vt[vd4 + 0][t] = (__bf16)v.x;
    vt[vd4 + 1][t] = (__bf16)v.y;
    vt[vd4 + 2][t] = (__bf16)v.z;
    vt[vd4 + 3][t] = (__bf16)v.w;
  }
  __syncthreads();
  {
    const int vd = tid >> 2, tseg = (tid & 3) * 32;
    uint4* o = (uint4*)(Vt + (size_t)bh * 65536 + (size_t)vd * 1024 + sb + tseg);
#pragma unroll
    for (int j = 0; j < 4; ++j)
      o[j] = *(const uint4*)&vt[vd][tseg + j * 8];
  }
}

// ---------------------------------------------------------------------------
// Barrier-free MFMA causal attention. ONE WAVE per block; wave owns 32 s-rows
// (2 s-tiles of 16). All operand fragments loaded directly from global in
// MFMA layout (L1/L2-served). Only the P (C/D -> A-operand) transform goes
// through a wave-private LDS buffer: 2x ds_write_b64 + 1x ds_read_b128 per
// s-tile per 32-t chunk; no __syncthreads anywhere.
// Grid: 2048 blocks = 32 sb2 (heavy-first) x 64 bh.
// ---------------------------------------------------------------------------
__global__ __launch_bounds__(64, 4) void attn_wave(
    const __bf16* __restrict__ Qg, const __bf16* __restrict__ Kg,
    const __bf16* __restrict__ Vt, const float* __restrict__ dist,
    const float* __restrict__ omega, __bf16* __restrict__ y) {
  __shared__ __bf16 zbuf[2][16][40];  // 80B row pitch: 2-way banks (free)

  const int idx = blockIdx.x;
  const int sb2 = 31 - (idx >> 6);     // heavy waves dispatch first
  const int bh = idx & 63;
  const int b = bh >> 3, h = bh & 7;
  const int lane = threadIdx.x & 63;
  const int l15 = lane & 15;
  const int q = lane >> 4;
  const float om = omega[h];
  const int s_base = sb2 * 32;

  const __bf16* Qp = Qg + (size_t)bh * 32768;
  const __bf16* Kp = Kg + (size_t)bh * 32768;
  const __bf16* Vp = Vt + (size_t)bh * 65536;
  const float* Dp = dist + ((size_t)b * 1024 + s_base) * 1024;  // rows s_base..

  // Q fragments (B-operand: n=l15 -> s, k=q*8+j), one per s-tile
  bf16x8 bq[2];
#pragma unroll
  for (int st = 0; st < 2; ++st)
    bq[st] = *(const bf16x8*)&Qp[(size_t)(s_base + st * 16 + l15) * 32 + q * 8];

  f32x4 acc[2][4];
#pragma unroll
  for (int st = 0; st < 2; ++st)
#pragma unroll
    for (int ni = 0; ni < 4; ++ni) acc[st][ni] = (f32x4){0.f, 0.f, 0.f, 0.f};
  float zsum[2] = {0.f, 0.f};

  const int nch = sb2 + 1;
  for (int c = 0; c < nch; ++c) {
    const int t0 = c * 32;
    // K fragments (A-operand: m=l15 -> t, k=q*8+j), two 16-t tiles
    const bf16x8 ak0 = *(const bf16x8*)&Kp[(size_t)(t0 + l15) * 32 + q * 8];
    const bf16x8 ak1 = *(const bf16x8*)&Kp[(size_t)(t0 + 16 + l15) * 32 + q * 8];
    // V fragments (B-operand: n=l15 -> vd_local, k=q*8+j -> t), 4 vd-tiles
    bf16x8 vb[4];
#pragma unroll
    for (int ni = 0; ni < 4; ++ni)
      vb[ni] = *(const bf16x8*)&Vp[(size_t)(ni * 16 + l15) * 1024 + t0 + q * 8];

#pragma unroll
    for (int st = 0; st < 2; ++st) {
      const int s = s_base + st * 16 + l15;  // this lane's s (stage 1)
      // dist: rows s, cols t0+q*4 (+16)
      const float4 dv0 = *(const float4*)&Dp[(size_t)(st * 16 + l15) * 1024 + t0 + q * 4];
      const float4 dv1 = *(const float4*)&Dp[(size_t)(st * 16 + l15) * 1024 + t0 + 16 + q * 4];
      // stage 1: S^T tiles; D[m=t=q*4+r][n=s=l15]
      f32x4 s0 = __builtin_amdgcn_mfma_f32_16x16x32_bf16(
          ak0, bq[st], (f32x4){0.f, 0.f, 0.f, 0.f}, 0, 0, 0);
      f32x4 s1 = __builtin_amdgcn_mfma_f32_16x16x32_bf16(
          ak1, bq[st], (f32x4){0.f, 0.f, 0.f, 0.f}, 0, 0, 0);
      float z0[4], z1[4];
#pragma unroll
      for (int r = 0; r < 4; ++r) {
        int t = t0 + q * 4 + r;
        float zv = __expf(s0[r] + __expf(-om * (&dv0.x)[r]) - 1.0f);
        z0[r] = (t <= s) ? zv : 0.0f;
        t += 16;
        zv = __expf(s1[r] + __expf(-om * (&dv1.x)[r]) - 1.0f);
        z1[r] = (t <= s) ? zv : 0.0f;
        zsum[st] += z0[r] + z1[r];
      }
      union { __hip_bfloat162 h2[2]; uint2 u; } p0, p1;
      p0.h2[0] = __float22bfloat162_rn(make_float2(z0[0], z0[1]));
      p0.h2[1] = __float22bfloat162_rn(make_float2(z0[2], z0[3]));
      p1.h2[0] = __float22bfloat162_rn(make_float2(z1[0], z1[1]));
      p1.h2[1] = __float22bfloat162_rn(make_float2(z1[2], z1[3]));
      *(uint2*)&zbuf[st][l15][q * 4] = p0.u;       // local t = q*4..q*4+3
      *(uint2*)&zbuf[st][l15][16 + q * 4] = p1.u;  // local t = 16+q*4..
    }
    // stage 2: A = z (m=s=l15, k=q*8+j -> t), B = V
#pragma unroll
    for (int st = 0; st < 2; ++st) {
      const bf16x8 az = *(const bf16x8*)&zbuf[st][l15][q * 8];
#pragma unroll
      for (int ni = 0; ni < 4; ++ni)
        acc[st][ni] = __builtin_amdgcn_mfma_f32_16x16x32_bf16(
            az, vb[ni], acc[st][ni], 0, 0, 0);
    }
  }

  // denominators: sum over quads (t-partition)
#pragma unroll
  for (int st = 0; st < 2; ++st) {
    zsum[st] += __shfl_xor(zsum[st], 16, 64);
    zsum[st] += __shfl_xor(zsum[st], 32, 64);
  }

  // epilogue: acc D layout col=l15 -> vd_local, row=q*4+r -> s-local
#pragma unroll
  for (int st = 0; st < 2; ++st) {
#pragma unroll
    for (int r = 0; r < 4; ++r) {
      const float dn = __shfl(zsum[st], q * 4 + r, 64);
      const float inv = 1.0f / (dn + 1.0f);
      __bf16* yp = &y[((size_t)b * 1024 + s_base + st * 16 + q * 4 + r) * 512 + h * 64 + l15];
#pragma unroll
      for (int ni = 0; ni < 4; ++ni)
        yp[ni * 16] = (__bf16)(acc[st][ni][r] * inv);
    }
  }
}

// ---------------------------------------------------------------------------
// Row-wise LayerNorm: one WAVE per row (4 rows / 256-thr block), shfl-only.
// ---------------------------------------------------------------------------
__global__ __launch_bounds__(256) void ln_kernel(
    const float* __restrict__ in, const float* __restrict__ w,
    const float* __restrict__ bvec, float* __restrict__ out,
    __bf16* __restrict__ outb) {
  const int row = blockIdx.x * 4 + (threadIdx.x >> 6);
  const int lane = threadIdx.x & 63;
  const float4* ip = (const float4*)(in + (size_t)row * 512);
  float4 a = ip[lane * 2], c = ip[lane * 2 + 1];
  float s = a.x + a.y + a.z + a.w + c.x + c.y + c.z + c.w;
#pragma unroll
  for (int off = 32; off > 0; off >>= 1) s += __shfl_xor(s, off, 64);
  const float mu = s * (1.0f / 512.0f);
  a.x -= mu; a.y -= mu; a.z -= mu; a.w -= mu;
  c.x -= mu; c.y -= mu; c.z -= mu; c.w -= mu;
  float s2 = a.x * a.x + a.y * a.y + a.z * a.z + a.w * a.w +
             c.x * c.x + c.y * c.y + c.z * c.z + c.w * c.w;
#pragma unroll
  for (int off = 32; off > 0; off >>= 1) s2 += __shfl_xor(s2, off, 64);
  const float inv = rsqrtf(s2 * (1.0f / 512.0f) + 1e-5f);
  const float4 w0 = ((const float4*)w)[lane * 2], w1 = ((const float4*)w)[lane * 2 + 1];
  const float4 b0 = ((const float4*)bvec)[lane * 2], b1 = ((const float4*)bvec)[lane * 2 + 1];
  float4 o0, o1;
  o0.x = a.x * inv * w0.x + b0.x; o0.y = a.y * inv * w0.y + b0.y;
  o0.z = a.z * inv * w0.z + b0.z; o0.w = a.w * inv * w0.w + b0.w;
  o1.x = c.x * inv * w1.x + b1.x; o1.y = c.y * inv * w1.y + b1.y;
  o1.z = c.z * inv * w1.z + b1.z; o1.w = c.w * inv * w1.w + b1.w;
  float4* op = (float4*)(out + (size_t)row * 512);
  op[lane * 2] = o0; op[lane * 2 + 1] = o1;
  if (outb) *(uint4*)&outb[(size_t)row * 512 + lane * 8] = pack8(o0, o1);
}

// ---------------------------------------------------------------------------
extern "C" void kernel_launch(void* const* d_in, const int* in_sizes, int n_in,
                              void* d_out, int out_size, void* d_ws, size_t ws_size,
                              hipStream_t stream) {
  const float* x = (const float*)d_in[0];
  // d_in[1] = attn_mask: deterministic causal triu(k=1) -> handled analytically
  const float* dist = (const float*)d_in[2];
  const float* Wq = (const float*)d_in[3];
  const float* Wk = (const float*)d_in[4];
  const float* Wv = (const float*)d_in[5];
  const float* omega = (const float*)d_in[6];
  const float* Wo = (const float*)d_in[7];
  const float* bo = (const float*)d_in[8];
  const float* Wf = (const float*)d_in[9];
  const float* bf_ = (const float*)d_in[10];
  const float* ln1w = (const float*)d_in[11];
  const float* ln1b = (const float*)d_in[12];
  const float* ln2w = (const float*)d_in[13];
  const float* ln2b = (const float*)d_in[14];
  float* out = (float*)d_out;

  // Workspace map (48 MB; phases never overlap in time):
  //  [ 0,32M): qkv fp32  ->  yb bf16 [0,8M) | t1 fp32 [8,24M) | t1b [24,32M)
  //  [32,48M): xb [32,40M) + Wcat [40,41M)  ->  Qg[32,36) Kg[36,40) Vt[40,48)
  //         -> Wob [32,32.5M) | Wfb [32.5,33M)
  char* base = (char*)d_ws;
  const size_t MB = 1 << 20;
  float* qkv = (float*)base;
  __bf16* yb = (__bf16*)base;
  float* t1 = (float*)(base + 8 * MB);
  __bf16* t1b = (__bf16*)(base + 24 * MB);
  __bf16* xb = (__bf16*)(base + 32 * MB);
  __bf16* Wcat = (__bf16*)(base + 40 * MB);
  __bf16* Qg = (__bf16*)(base + 32 * MB);
  __bf16* Kg = (__bf16*)(base + 36 * MB);
  __bf16* Vt = (__bf16*)(base + 40 * MB);
  __bf16* Wob = (__bf16*)(base + 32 * MB);
  __bf16* Wfb = (__bf16*)(base + 32 * MB + 512 * 1024);

  dim3 blk(256);
  // 0. x, Wq|Wk|Wv -> bf16
  cvt_pre<<<dim3(2304), blk, 0, stream>>>(x, Wq, Wk, Wv, xb, Wcat);
  // 1. QKV projection -> qkv fp32
  gemm_bf16<0><<<dim3(8, 64), blk, 0, stream>>>(xb, Wcat, nullptr, nullptr,
                                                qkv, 1024);
  // 2. prep: l2norm q,k -> Qg/Kg; V -> Vt
  prep_qkv<<<dim3(64, 8), blk, 0, stream>>>(qkv, Qg, Kg, Vt);
  // 3. barrier-free MFMA causal attention -> yb bf16
  attn_wave<<<dim3(2048), dim3(64), 0, stream>>>(Qg, Kg, Vt, dist, omega, yb);
  // 3b. Wo,Wf -> bf16 (Qg region dead)
  cvt_wof<<<dim3(256), blk, 0, stream>>>(Wo, Wf, Wob, Wfb);
  // 4. out-proj + bias + residual -> t1 fp32
  gemm_bf16<1><<<dim3(4, 64), blk, 0, stream>>>(yb, Wob, bo, x, t1, 512);
  // 5. LayerNorm1: t1 in-place + t1b bf16
  ln_kernel<<<dim3(2048), blk, 0, stream>>>(t1, ln1w, ln1b, t1, t1b);
  // 6. FFN + leaky-relu + residual -> d_out
  gemm_bf16<2><<<dim3(4, 64), blk, 0, stream>>>(t1b, Wfb, bf_, t1, out, 512);
  // 7. LayerNorm2 in-place on d_out
  ln_kernel<<<dim3(2048), blk, 0, stream>>>(out, ln2w, ln2b, out, nullptr);
}

// Round 7
// 246.348 us; speedup vs baseline: 1.0785x; 1.0785x over previous
//
#include <hip/hip_runtime.h>
#include <hip/hip_bf16.h>
#include <math.h>
#include <stdint.h>

// Problem constants
#define BB 8
#define SS 1024
#define DMM 512
#define HH 8
#define DKK 32
#define DHH 64
// M = BB*SS = 8192

typedef __bf16 bf16x8 __attribute__((ext_vector_type(8)));
typedef float f32x4 __attribute__((ext_vector_type(4)));

// async 16B global->LDS (gfx950). LDS dest = wave-uniform base + lane*16.
__device__ __forceinline__ void gll16(const void* g, void* l) {
  __builtin_amdgcn_global_load_lds(
      (const __attribute__((address_space(1))) void*)(uintptr_t)g,
      (__attribute__((address_space(3))) void*)(uint32_t)(uintptr_t)l,
      16, 0, 0);
}

__device__ __forceinline__ uint4 pack8(const float4 a, const float4 b) {
  union { __hip_bfloat162 h2[4]; uint4 u; } p;
  p.h2[0] = __float22bfloat162_rn(make_float2(a.x, a.y));
  p.h2[1] = __float22bfloat162_rn(make_float2(a.z, a.w));
  p.h2[2] = __float22bfloat162_rn(make_float2(b.x, b.y));
  p.h2[3] = __float22bfloat162_rn(make_float2(b.z, b.w));
  return p.u;
}

// ---------------------------------------------------------------------------
// One-shot fp32->bf16 conversion of x, Wq|Wk|Wv (->Wcat), Wo, Wf. 2560 blocks.
// ---------------------------------------------------------------------------
__global__ __launch_bounds__(256) void cvt_all(
    const float* __restrict__ x, const float* __restrict__ Wq,
    const float* __restrict__ Wk, const float* __restrict__ Wv,
    const float* __restrict__ Wo, const float* __restrict__ Wf,
    __bf16* __restrict__ xb, __bf16* __restrict__ Wcat,
    __bf16* __restrict__ Wob, __bf16* __restrict__ Wfb) {
  size_t i = ((size_t)blockIdx.x * 256 + threadIdx.x) * 8;
  const float* s;
  __bf16* d;
  size_t off;
  if (i < 4194304) { s = x; d = xb + i; off = i; }
  else {
    size_t j = i - 4194304;
    if (j < 524288) {  // Wcat
      d = Wcat + j;
      if (j < 131072) { s = Wq; off = j; }
      else if (j < 262144) { s = Wk; off = j - 131072; }
      else { s = Wv; off = j - 262144; }
    } else {
      size_t jj = j - 524288;
      if (jj < 262144) { s = Wo; d = Wob + jj; off = jj; }
      else { s = Wf; d = Wfb + (jj - 262144); off = jj - 262144; }
    }
  }
  float4 a = *(const float4*)&s[off];
  float4 b = *(const float4*)&s[off + 4];
  *(uint4*)d = pack8(a, b);
}

// ---------------------------------------------------------------------------
// QKV GEMM with FUSED epilogue: fp32 acc -> l2norm(q,k) -> bf16 Qg/Kg planes
// [bh][1024 s][32 k]; v -> bf16 Vrow [m][512]. Core = validated gemm_bf16.
// l2norm: 32-col head group = ni-pair; sum-of-squares reduced across the 16
// lanes of a row-group via shfl_xor(1,2,4,8) (same quad => same row).
// ---------------------------------------------------------------------------
__global__ __launch_bounds__(256) void gemm_qkv(
    const __bf16* __restrict__ A, const __bf16* __restrict__ W,
    __bf16* __restrict__ Qg, __bf16* __restrict__ Kg,
    __bf16* __restrict__ Vrow) {
  __shared__ __bf16 As[128 * 32];
  __shared__ __bf16 Bs[128 * 32];
  const int tid = threadIdx.x;
  const int n0 = blockIdx.x * 128;
  const int m0 = blockIdx.y * 128;
  const int lane = tid & 63;
  const int w = tid >> 6;
  const int wm = (w & 1) * 64, wn = (w >> 1) * 64;
  const int fr = lane & 15, quad = lane >> 4;
  const int srow = lane >> 2;
  const int schunk = (lane & 3) ^ ((lane >> 3) & 3);

  f32x4 acc[4][4];
#pragma unroll
  for (int mi = 0; mi < 4; ++mi)
#pragma unroll
    for (int ni = 0; ni < 4; ++ni) acc[mi][ni] = (f32x4){0.f, 0.f, 0.f, 0.f};

  for (int kt = 0; kt < 512; kt += 32) {
    __syncthreads();
#pragma unroll
    for (int j = 0; j < 2; ++j) {
      const int seg = w * 2 + j;
      const int row = seg * 16 + srow;
      gll16(&A[(size_t)(m0 + row) * 512 + kt + schunk * 8], &As[seg * 512]);
      gll16(&W[(size_t)(n0 + row) * 512 + kt + schunk * 8], &Bs[seg * 512]);
    }
    __syncthreads();

    bf16x8 af[4], bf[4];
    const int rsw = (quad ^ ((fr >> 1) & 3)) * 8;
#pragma unroll
    for (int mi = 0; mi < 4; ++mi)
      af[mi] = *(const bf16x8*)&As[(wm + mi * 16 + fr) * 32 + rsw];
#pragma unroll
    for (int ni = 0; ni < 4; ++ni)
      bf[ni] = *(const bf16x8*)&Bs[(wn + ni * 16 + fr) * 32 + rsw];
#pragma unroll
    for (int mi = 0; mi < 4; ++mi)
#pragma unroll
      for (int ni = 0; ni < 4; ++ni)
        acc[mi][ni] = __builtin_amdgcn_mfma_f32_16x16x32_bf16(
            af[mi], bf[ni], acc[mi][ni], 0, 0, 0);
  }

  const int er = quad * 4;
  const int ec = fr;
  if (n0 < 512) {
    const bool isq = (n0 < 256);
    __bf16* G = isq ? Qg : Kg;
    const int nb = isq ? n0 : n0 - 256;
#pragma unroll
    for (int mi = 0; mi < 4; ++mi) {
#pragma unroll
      for (int p = 0; p < 2; ++p) {
        const int hh = (nb + wn + p * 32) >> 5;
#pragma unroll
        for (int r = 0; r < 4; ++r) {
          float v0 = acc[mi][2 * p][r], v1 = acc[mi][2 * p + 1][r];
          float ss = v0 * v0 + v1 * v1;
          ss += __shfl_xor(ss, 1, 64);
          ss += __shfl_xor(ss, 2, 64);
          ss += __shfl_xor(ss, 4, 64);
          ss += __shfl_xor(ss, 8, 64);
          const float sc = 1.0f / fmaxf(sqrtf(ss), 1e-12f);
          const int mm = m0 + wm + mi * 16 + er + r;
          const int bb = mm >> 10, s = mm & 1023;
          __bf16* gp = G + ((size_t)(bb * 8 + hh) * 1024 + s) * 32;
          gp[ec] = (__bf16)(v0 * sc);
          gp[16 + ec] = (__bf16)(v1 * sc);
        }
      }
    }
  } else {
#pragma unroll
    for (int mi = 0; mi < 4; ++mi)
#pragma unroll
      for (int ni = 0; ni < 4; ++ni) {
        const int n = n0 - 512 + wn + ni * 16 + ec;
#pragma unroll
        for (int r = 0; r < 4; ++r) {
          const int mm = m0 + wm + mi * 16 + er + r;
          Vrow[(size_t)mm * 512 + n] = (__bf16)acc[mi][ni][r];
        }
      }
  }
}

// ---------------------------------------------------------------------------
// bf16-input MFMA GEMM, MODE 1: +bias+resid; MODE 2: resid+leaky(v+bias).
// (validated R5 structure)
// ---------------------------------------------------------------------------
template <int MODE>
__global__ __launch_bounds__(256) void gemm_bf16(
    const __bf16* __restrict__ A, const __bf16* __restrict__ W,
    const float* __restrict__ bias, const float* __restrict__ resid,
    float* __restrict__ C, int N) {
  __shared__ __bf16 As[128 * 32];
  __shared__ __bf16 Bs[128 * 32];
  const int tid = threadIdx.x;
  const int n0 = blockIdx.x * 128;
  const int m0 = blockIdx.y * 128;
  const int lane = tid & 63;
  const int w = tid >> 6;
  const int wm = (w & 1) * 64, wn = (w >> 1) * 64;
  const int fr = lane & 15, quad = lane >> 4;
  const int srow = lane >> 2;
  const int schunk = (lane & 3) ^ ((lane >> 3) & 3);

  f32x4 acc[4][4];
#pragma unroll
  for (int mi = 0; mi < 4; ++mi)
#pragma unroll
    for (int ni = 0; ni < 4; ++ni) acc[mi][ni] = (f32x4){0.f, 0.f, 0.f, 0.f};

  for (int kt = 0; kt < 512; kt += 32) {
    __syncthreads();
#pragma unroll
    for (int j = 0; j < 2; ++j) {
      const int seg = w * 2 + j;
      const int row = seg * 16 + srow;
      gll16(&A[(size_t)(m0 + row) * 512 + kt + schunk * 8], &As[seg * 512]);
      gll16(&W[(size_t)(n0 + row) * 512 + kt + schunk * 8], &Bs[seg * 512]);
    }
    __syncthreads();

    bf16x8 af[4], bf[4];
    const int rsw = (quad ^ ((fr >> 1) & 3)) * 8;
#pragma unroll
    for (int mi = 0; mi < 4; ++mi)
      af[mi] = *(const bf16x8*)&As[(wm + mi * 16 + fr) * 32 + rsw];
#pragma unroll
    for (int ni = 0; ni < 4; ++ni)
      bf[ni] = *(const bf16x8*)&Bs[(wn + ni * 16 + fr) * 32 + rsw];
#pragma unroll
    for (int mi = 0; mi < 4; ++mi)
#pragma unroll
      for (int ni = 0; ni < 4; ++ni)
        acc[mi][ni] = __builtin_amdgcn_mfma_f32_16x16x32_bf16(
            af[mi], bf[ni], acc[mi][ni], 0, 0, 0);
  }

  const int er = quad * 4;
  const int ec = fr;
#pragma unroll
  for (int mi = 0; mi < 4; ++mi) {
#pragma unroll
    for (int ni = 0; ni < 4; ++ni) {
      const int n = n0 + wn + ni * 16 + ec;
      float bsv = bias[n];
#pragma unroll
      for (int r = 0; r < 4; ++r) {
        const int m = m0 + wm + mi * 16 + er + r;
        float v = acc[mi][ni][r];
        if (MODE == 1) {
          v += bsv + resid[(size_t)m * 512 + n];
        } else {
          float g = v + bsv;
          g = g > 0.f ? g : 0.01f * g;
          v = resid[(size_t)m * 512 + n] + g;
        }
        C[(size_t)m * N + n] = v;
      }
    }
  }
}

// ---------------------------------------------------------------------------
// V transpose: Vrow bf16 [b*1024+t][h*64+vd] -> Vt [bh][64 vd][1024 t].
// Grid (64 bh, 8 t-chunks of 128).
// ---------------------------------------------------------------------------
__global__ __launch_bounds__(256) void v_transpose(
    const __bf16* __restrict__ Vrow, __bf16* __restrict__ Vt) {
  __shared__ __bf16 vt[64][136];
  const int bh = blockIdx.x;
  const int b = bh >> 3, h = bh & 7;
  const int sb = blockIdx.y * 128;
  const int tid = threadIdx.x;
#pragma unroll
  for (int i = 0; i < 8; ++i) {
    int idx = tid + i * 256;              // 2048 = 128 t x 16 vd4-groups
    int t = idx >> 4, vd4 = (idx & 15) * 4;
    union { uint2 u; __bf16 e[4]; } v;
    v.u = *(const uint2*)&Vrow[((size_t)(b * 1024 + sb + t)) * 512 + h * 64 + vd4];
    vt[vd4 + 0][t] = v.e[0];
    vt[vd4 + 1][t] = v.e[1];
    vt[vd4 + 2][t] = v.e[2];
    vt[vd4 + 3][t] = v.e[3];
  }
  __syncthreads();
  {
    const int vd = tid >> 2, tseg = (tid & 3) * 32;
    uint4* o = (uint4*)(Vt + (size_t)bh * 65536 + (size_t)vd * 1024 + sb + tseg);
#pragma unroll
    for (int j = 0; j < 4; ++j)
      o[j] = *(const uint4*)&vt[vd][tseg + j * 8];
  }
}

// ---------------------------------------------------------------------------
// Hybrid MFMA causal attention. Block = 4 waves, 64 s-rows; wave owns 16.
// K/V staged cooperatively (shared LDS, 2 barriers/tile); Q in registers;
// z-transform via wave-PRIVATE LDS buffer (lgkmcnt only, no barrier).
// LDS 21.5 KB -> 7 blocks/CU.
// ---------------------------------------------------------------------------
__global__ __launch_bounds__(256) void attn_fused(
    const __bf16* __restrict__ Qg, const __bf16* __restrict__ Kg,
    const __bf16* __restrict__ Vt, const float* __restrict__ dist,
    const float* __restrict__ omega, __bf16* __restrict__ y) {
  __shared__ __bf16 Ks[64 * 32];
  __shared__ __bf16 Vs[64 * 64];
  __shared__ __bf16 zbuf[4][16][72];

  const int b = blockIdx.x;
  const int s0 = (15 - blockIdx.y) * 64;   // heavy tiles dispatch first
  const int h = blockIdx.z;
  const int bh = b * 8 + h;
  const int tid = threadIdx.x;
  const int lane = tid & 63;
  const int w = tid >> 6;
  const int q = lane >> 4;
  const int m = lane & 15;
  const float om = omega[h];

  const int sl = s0 + w * 16 + m;          // lane's s (stage1 col, stage2 row)
  const bf16x8 bq = *(const bf16x8*)&Qg[((size_t)bh * 1024 + sl) * 32 + q * 8];
  const int kswz = (q ^ ((m >> 1) & 3)) * 8;

  f32x4 acc[4];
#pragma unroll
  for (int ni = 0; ni < 4; ++ni) acc[ni] = (f32x4){0.f, 0.f, 0.f, 0.f};
  float zsum = 0.0f;
  const int ntiles = (s0 >> 6) + 1;

  for (int tt = 0; tt < ntiles; ++tt) {
    const int t0 = tt * 64;
    __syncthreads();  // prior tile's Ks/Vs reads complete
    // stage K tile (64 t x 32 k = 4 KB)
    {
      int row = tid >> 2, p = tid & 3;
      uint4 v = *(const uint4*)&Kg[((size_t)bh * 1024 + t0 + row) * 32 + p * 8];
      *(uint4*)&Ks[row * 32 + ((p ^ ((row >> 1) & 3)) * 8)] = v;
    }
    // stage V^T tile (64 vd x 64 t = 8 KB)
#pragma unroll
    for (int i = 0; i < 2; ++i) {
      int idx = tid + i * 256;
      int vd = idx >> 3, p = idx & 7;
      uint4 v = *(const uint4*)&Vt[(size_t)bh * 65536 + (size_t)vd * 1024 + t0 + p * 8];
      *(uint4*)&Vs[vd * 64 + ((p ^ (vd & 7)) * 8)] = v;
    }
    // dist prefetch: row sl, cols t0+16mi+q*4
    float4 dv[4];
#pragma unroll
    for (int mi = 0; mi < 4; ++mi)
      dv[mi] = *(const float4*)&dist[((size_t)b * 1024 + sl) * 1024 + t0 + 16 * mi + q * 4];
    __syncthreads();  // staging visible

    // stage 1: A = K (m=t), B = Q (n=s); 4 t-subtiles
#pragma unroll
    for (int mi = 0; mi < 4; ++mi) {
      const bf16x8 ak = *(const bf16x8*)&Ks[(16 * mi + m) * 32 + kswz];
      f32x4 s4 = __builtin_amdgcn_mfma_f32_16x16x32_bf16(
          ak, bq, (f32x4){0.f, 0.f, 0.f, 0.f}, 0, 0, 0);
      float zr[4];
#pragma unroll
      for (int r = 0; r < 4; ++r) {
        const int t = t0 + 16 * mi + q * 4 + r;
        float zv = __expf(s4[r] + __expf(-om * (&dv[mi].x)[r]) - 1.0f);
        zr[r] = (t <= sl) ? zv : 0.0f;
        zsum += zr[r];
      }
      union { __hip_bfloat162 h2[2]; uint2 u; } pz;
      pz.h2[0] = __float22bfloat162_rn(make_float2(zr[0], zr[1]));
      pz.h2[1] = __float22bfloat162_rn(make_float2(zr[2], zr[3]));
      *(uint2*)&zbuf[w][m][16 * mi + q * 4] = pz.u;  // row = s-local = m
    }
    // stage 2 (wave-private z; lgkmcnt ordering only, no barrier)
    const bf16x8 az0 = *(const bf16x8*)&zbuf[w][m][q * 8];
    const bf16x8 az1 = *(const bf16x8*)&zbuf[w][m][32 + q * 8];
#pragma unroll
    for (int ni = 0; ni < 4; ++ni) {
      const bf16x8 vb0 = *(const bf16x8*)&Vs[(16 * ni + m) * 64 + ((q ^ (m & 7)) * 8)];
      const bf16x8 vb1 = *(const bf16x8*)&Vs[(16 * ni + m) * 64 + (((q + 4) ^ (m & 7)) * 8)];
      acc[ni] = __builtin_amdgcn_mfma_f32_16x16x32_bf16(az0, vb0, acc[ni], 0, 0, 0);
      acc[ni] = __builtin_amdgcn_mfma_f32_16x16x32_bf16(az1, vb1, acc[ni], 0, 0, 0);
    }
  }

  // denominator: lane's s determined by m only -> sum across the 4 quads
  zsum += __shfl_xor(zsum, 16, 64);
  zsum += __shfl_xor(zsum, 32, 64);

  // epilogue: acc D rows = s-local q*4+r, cols vd = 16ni+m
#pragma unroll
  for (int r = 0; r < 4; ++r) {
    const float dn = __shfl(zsum, q * 4 + r, 64);
    const float inv = 1.0f / (dn + 1.0f);
    __bf16* yp = &y[((size_t)b * 1024 + s0 + w * 16 + q * 4 + r) * 512 + h * 64 + m];
#pragma unroll
    for (int ni = 0; ni < 4; ++ni)
      yp[ni * 16] = (__bf16)(acc[ni][r] * inv);
  }
}

// ---------------------------------------------------------------------------
// Row-wise LayerNorm: one wave per row, shfl-only (validated R6).
// ---------------------------------------------------------------------------
__global__ __launch_bounds__(256) void ln_kernel(
    const float* __restrict__ in, const float* __restrict__ w,
    const float* __restrict__ bvec, float* __restrict__ out,
    __bf16* __restrict__ outb) {
  const int row = blockIdx.x * 4 + (threadIdx.x >> 6);
  const int lane = threadIdx.x & 63;
  const float4* ip = (const float4*)(in + (size_t)row * 512);
  float4 a = ip[lane * 2], c = ip[lane * 2 + 1];
  float s = a.x + a.y + a.z + a.w + c.x + c.y + c.z + c.w;
#pragma unroll
  for (int off = 32; off > 0; off >>= 1) s += __shfl_xor(s, off, 64);
  const float mu = s * (1.0f / 512.0f);
  a.x -= mu; a.y -= mu; a.z -= mu; a.w -= mu;
  c.x -= mu; c.y -= mu; c.z -= mu; c.w -= mu;
  float s2 = a.x * a.x + a.y * a.y + a.z * a.z + a.w * a.w +
             c.x * c.x + c.y * c.y + c.z * c.z + c.w * c.w;
#pragma unroll
  for (int off = 32; off > 0; off >>= 1) s2 += __shfl_xor(s2, off, 64);
  const float inv = rsqrtf(s2 * (1.0f / 512.0f) + 1e-5f);
  const float4 w0 = ((const float4*)w)[lane * 2], w1 = ((const float4*)w)[lane * 2 + 1];
  const float4 b0 = ((const float4*)bvec)[lane * 2], b1 = ((const float4*)bvec)[lane * 2 + 1];
  float4 o0, o1;
  o0.x = a.x * inv * w0.x + b0.x; o0.y = a.y * inv * w0.y + b0.y;
  o0.z = a.z * inv * w0.z + b0.z; o0.w = a.w * inv * w0.w + b0.w;
  o1.x = c.x * inv * w1.x + b1.x; o1.y = c.y * inv * w1.y + b1.y;
  o1.z = c.z * inv * w1.z + b1.z; o1.w = c.w * inv * w1.w + b1.w;
  float4* op = (float4*)(out + (size_t)row * 512);
  op[lane * 2] = o0; op[lane * 2 + 1] = o1;
  if (outb) *(uint4*)&outb[(size_t)row * 512 + lane * 8] = pack8(o0, o1);
}

// ---------------------------------------------------------------------------
extern "C" void kernel_launch(void* const* d_in, const int* in_sizes, int n_in,
                              void* d_out, int out_size, void* d_ws, size_t ws_size,
                              hipStream_t stream) {
  const float* x = (const float*)d_in[0];
  // d_in[1] = attn_mask: deterministic causal triu(k=1) -> handled analytically
  const float* dist = (const float*)d_in[2];
  const float* Wq = (const float*)d_in[3];
  const float* Wk = (const float*)d_in[4];
  const float* Wv = (const float*)d_in[5];
  const float* omega = (const float*)d_in[6];
  const float* Wo = (const float*)d_in[7];
  const float* bo = (const float*)d_in[8];
  const float* Wf = (const float*)d_in[9];
  const float* bf_ = (const float*)d_in[10];
  const float* ln1w = (const float*)d_in[11];
  const float* ln1b = (const float*)d_in[12];
  const float* ln2w = (const float*)d_in[13];
  const float* ln2b = (const float*)d_in[14];
  float* out = (float*)d_out;

  // Workspace map (42 MB used; non-overlapping in time):
  //  [0,8):  xb (dead after gemm_qkv) -> yb (attn out)
  //  [8,9):  Wcat   [9,9.5): Wob   [9.5,10): Wfb
  //  [10,14): Qg   [14,18): Kg          (dead after attn)
  //  [18,26): Vrow (dead after v_transpose)
  //  [26,34): Vt   (dead after attn)
  //  [18,34): t1 fp32 (written by gemm1, AFTER attn)
  //  [34,42): t1b bf16
  char* base = (char*)d_ws;
  const size_t MB = 1 << 20;
  __bf16* xb = (__bf16*)base;
  __bf16* yb = (__bf16*)base;
  __bf16* Wcat = (__bf16*)(base + 8 * MB);
  __bf16* Wob = (__bf16*)(base + 9 * MB);
  __bf16* Wfb = (__bf16*)(base + 9 * MB + 512 * 1024);
  __bf16* Qg = (__bf16*)(base + 10 * MB);
  __bf16* Kg = (__bf16*)(base + 14 * MB);
  __bf16* Vrow = (__bf16*)(base + 18 * MB);
  __bf16* Vt = (__bf16*)(base + 26 * MB);
  float* t1 = (float*)(base + 18 * MB);
  __bf16* t1b = (__bf16*)(base + 34 * MB);

  dim3 blk(256);
  // 0. all fp32 -> bf16 conversions in one pass
  cvt_all<<<dim3(2560), blk, 0, stream>>>(x, Wq, Wk, Wv, Wo, Wf,
                                          xb, Wcat, Wob, Wfb);
  // 1. QKV projection with fused l2norm -> Qg/Kg bf16 + Vrow bf16
  gemm_qkv<<<dim3(8, 64), blk, 0, stream>>>(xb, Wcat, Qg, Kg, Vrow);
  // 2. Vrow -> Vt (transposed)
  v_transpose<<<dim3(64, 8), blk, 0, stream>>>(Vrow, Vt);
  // 3. hybrid MFMA causal attention -> yb bf16
  attn_fused<<<dim3(8, 16, 8), blk, 0, stream>>>(Qg, Kg, Vt, dist, omega, yb);
  // 4. out-proj + bias + residual -> t1 fp32
  gemm_bf16<1><<<dim3(4, 64), blk, 0, stream>>>(yb, Wob, bo, x, t1, 512);
  // 5. LayerNorm1: t1 in-place + t1b bf16
  ln_kernel<<<dim3(2048), blk, 0, stream>>>(t1, ln1w, ln1b, t1, t1b);
  // 6. FFN + leaky-relu + residual -> d_out
  gemm_bf16<2><<<dim3(4, 64), blk, 0, stream>>>(t1b, Wfb, bf_, t1, out, 512);
  // 7. LayerNorm2 in-place on d_out
  ln_kernel<<<dim3(2048), blk, 0, stream>>>(out, ln2w, ln2b, out, nullptr);
}